// Round 5
// baseline (634.396 us; speedup 1.0000x reference)
//
#include <hip/hip_runtime.h>

typedef __bf16 bf16;
typedef __bf16 bf16x8 __attribute__((ext_vector_type(8)));
typedef float  f32x4  __attribute__((ext_vector_type(4)));

#define MFMA16(a, b, c) __builtin_amdgcn_mfma_f32_16x16x32_bf16((a), (b), (c), 0, 0, 0)

// async global->LDS, 16B per lane; LDS dest = wave-uniform base + lane*16
#define GLOAD_LDS16(gptr, lptr)                                              \
    __builtin_amdgcn_global_load_lds(                                        \
        (const __attribute__((address_space(1))) unsigned int*)(gptr),       \
        (__attribute__((address_space(3))) unsigned int*)(lptr), 16, 0, 0)

constexpr int kDM = 1024;
constexpr int kNTOK = 32768;   // V token count (vt row stride)

static __device__ inline f32x4 zero4() { f32x4 z = {0.f, 0.f, 0.f, 0.f}; return z; }

// ---------------------------------------------------------------------------
// Streaming fp32 -> bf16 convert for q and k in ONE launch (RNE rounding).
// dst layout: q bf16 [2048*1024] followed by k bf16 [32768*1024].
// ---------------------------------------------------------------------------
__global__ __launch_bounds__(256) void cvt_qk(
    const float* __restrict__ q, const float* __restrict__ k, bf16* __restrict__ dst)
{
    const int q8 = 262144, tot = q8 + 4194304;
    int idx = blockIdx.x * 256 + threadIdx.x;
    const int stride = gridDim.x * 256;
    for (; idx < tot; idx += stride) {
        const float* s = (idx < q8) ? q + (size_t)idx * 8
                                    : k + (size_t)(idx - q8) * 8;
        const float4 u0 = *(const float4*)s;
        const float4 u1 = *(const float4*)(s + 4);
        bf16x8 w;
        w[0] = (bf16)u0.x; w[1] = (bf16)u0.y; w[2] = (bf16)u0.z; w[3] = (bf16)u0.w;
        w[4] = (bf16)u1.x; w[5] = (bf16)u1.y; w[6] = (bf16)u1.z; w[7] = (bf16)u1.w;
        *(bf16x8*)&dst[(size_t)idx * 8] = w;
    }
}

__global__ __launch_bounds__(256) void cvt_bf16(
    const float* __restrict__ src, bf16* __restrict__ dst, int n8)
{
    int idx = blockIdx.x * 256 + threadIdx.x;
    const int stride = gridDim.x * 256;
    for (; idx < n8; idx += stride) {
        const float4 u0 = *(const float4*)(src + (size_t)idx * 8);
        const float4 u1 = *(const float4*)(src + (size_t)idx * 8 + 4);
        bf16x8 w;
        w[0] = (bf16)u0.x; w[1] = (bf16)u0.y; w[2] = (bf16)u0.z; w[3] = (bf16)u0.w;
        w[4] = (bf16)u1.x; w[5] = (bf16)u1.y; w[6] = (bf16)u1.z; w[7] = (bf16)u1.w;
        *(bf16x8*)&dst[(size_t)idx * 8] = w;
    }
}

// ---------------------------------------------------------------------------
// All three W fp32 [k][n] -> Wt bf16 [n][k] transposes in one launch.
// ---------------------------------------------------------------------------
__global__ __launch_bounds__(256) void transpose_all(
    const float* __restrict__ Wq, const float* __restrict__ Wk,
    const float* __restrict__ Wv, bf16* __restrict__ Wqt,
    bf16* __restrict__ Wkt, bf16* __restrict__ Wvt)
{
    __shared__ bf16 T[64][68];
    const float* W = (blockIdx.z == 0) ? Wq : (blockIdx.z == 1) ? Wk : Wv;
    bf16* Wt       = (blockIdx.z == 0) ? Wqt : (blockIdx.z == 1) ? Wkt : Wvt;
    const int tid = threadIdx.x;
    const int n0 = blockIdx.x * 64, k0 = blockIdx.y * 64;
    #pragma unroll
    for (int i = 0; i < 4; i++) {
        const int kk = (tid >> 4) + i * 16, nn4 = (tid & 15) * 4;
        float4 v = *(const float4*)&W[(size_t)(k0 + kk) * kDM + n0 + nn4];
        T[nn4 + 0][kk] = (bf16)v.x; T[nn4 + 1][kk] = (bf16)v.y;
        T[nn4 + 2][kk] = (bf16)v.z; T[nn4 + 3][kk] = (bf16)v.w;
    }
    __syncthreads();
    #pragma unroll
    for (int i = 0; i < 4; i++) {
        const int nn = (tid >> 4) + i * 16, kc = (tid & 15) * 4;
        *(ushort4*)&Wt[(size_t)(n0 + nn) * kDM + k0 + kc] = *(const ushort4*)&T[nn][kc];
    }
}

// ---------------------------------------------------------------------------
// 256x256 GEMM, BK=64, 8 waves (2M x 4N), quadrant-phase schedule (T3+T4+T5).
// LDS 128KB: A[d][h] / B[d][h] = 4 x 16KB half-regions per operand
// (d = K-tile parity, h = row-half).  Both operands staged bf16 via
// global_load_lds w=16 (linear dest, XOR-pre-swizzled source).
// Per K-tile w (4 phases):
//   p0: read a(ih0) 8x b128 + b(jh0) 4x | stage B0(w+1) | bar | 16 MFMA | bar
//   p1: read b(jh1) 4x                  | stage B1(w+1) | bar | 16 MFMA | bar
//   p2: read a(ih1) 8x                  | --            | bar | 16 MFMA | bar
//   p3: read b(jh0) 4x                  | stage A0,A1(w+2) | bar | 16 MFMA |
//       vmcnt(4) (leaves A(w+2) in flight) | bar
// Region-lifetime proof: A[d][h] read at p0,p2 of its window -> staged at p3;
// B[d][h] read p0,p1,p3 -> staged at next window's p0/p1 (other parity free).
// vmcnt(4) once per K-tile forces tile w+1 complete, never drains to 0
// until the tail (w=14).
// MODE 1: slow RoPE (q).  MODE 2: fast RoPE (k).  MODE 3: V^T store.
// ---------------------------------------------------------------------------
__device__ __forceinline__ void gemm256_body(
    const bf16* __restrict__ X, const bf16* __restrict__ Wt,
    const float* __restrict__ bias, bf16* __restrict__ out,
    int m0, int n0, int mode)
{
    __shared__ char smem[131072];
    bf16* SA = (bf16*)smem;              // A[d][h]: d*16384 + h*8192 elems
    bf16* SB = (bf16*)(smem + 65536);

    const int tid  = threadIdx.x;
    const int wave = tid >> 6;
    const int lane = tid & 63;
    const int quad = lane >> 4, l16 = lane & 15;
    const int wr   = wave >> 2;          // 0..1 (M half)
    const int wc   = wave & 3;           // 0..3 (N quarter)
    const int r8   = lane >> 3, j8 = lane & 7;
    const int c0   = wave * 2;           // staging chunk base (2 chunks/wave)

    // Pre-swizzled global staging bases (row&7 == r8 for every chunk row).
    const bf16* aS00 = X  + (size_t)(m0 +   0 + c0 * 8 + r8) * kDM + (j8 ^ r8) * 8;
    const bf16* aS01 = X  + (size_t)(m0 +   8 + c0 * 8 + r8) * kDM + (j8 ^ r8) * 8;
    const bf16* aS10 = X  + (size_t)(m0 + 128 + c0 * 8 + r8) * kDM + (j8 ^ r8) * 8;
    const bf16* aS11 = X  + (size_t)(m0 + 136 + c0 * 8 + r8) * kDM + (j8 ^ r8) * 8;
    const bf16* bS00 = Wt + (size_t)(n0 +   0 + c0 * 8 + r8) * kDM + (j8 ^ r8) * 8;
    const bf16* bS01 = Wt + (size_t)(n0 +   8 + c0 * 8 + r8) * kDM + (j8 ^ r8) * 8;
    const bf16* bS10 = Wt + (size_t)(n0 + 128 + c0 * 8 + r8) * kDM + (j8 ^ r8) * 8;
    const bf16* bS11 = Wt + (size_t)(n0 + 136 + c0 * 8 + r8) * kDM + (j8 ^ r8) * 8;

    auto stageA = [&](int T, int h) {
        bf16* dst = SA + (T & 1) * 16384 + h * 8192 + c0 * 512;
        if (h == 0) { GLOAD_LDS16(aS00 + (size_t)T * 64, dst);
                      GLOAD_LDS16(aS01 + (size_t)T * 64, dst + 512); }
        else        { GLOAD_LDS16(aS10 + (size_t)T * 64, dst);
                      GLOAD_LDS16(aS11 + (size_t)T * 64, dst + 512); }
    };
    auto stageB = [&](int T, int h) {
        bf16* dst = SB + (T & 1) * 16384 + h * 8192 + c0 * 512;
        if (h == 0) { GLOAD_LDS16(bS00 + (size_t)T * 64, dst);
                      GLOAD_LDS16(bS01 + (size_t)T * 64, dst + 512); }
        else        { GLOAD_LDS16(bS10 + (size_t)T * 64, dst);
                      GLOAD_LDS16(bS11 + (size_t)T * 64, dst + 512); }
    };

    f32x4 acc[8][4];
    #pragma unroll
    for (int i = 0; i < 8; i++)
        #pragma unroll
        for (int j = 0; j < 4; j++) acc[i][j] = zero4();

    // ---- prologue: tile 0 fully + A-halves of tile 1; vmcnt(4) leaves A(1) ----
    stageA(0, 0); stageA(0, 1); stageB(0, 0); stageB(0, 1);
    stageA(1, 0); stageA(1, 1);
    asm volatile("s_waitcnt vmcnt(4)" ::: "memory");
    __builtin_amdgcn_s_barrier();
    __builtin_amdgcn_sched_barrier(0);

    bf16x8 af[4][2], bf[2][2];

    for (int w = 0; w < 16; ++w) {
        const int d = w & 1;
        const bf16* Acur = SA + d * 16384 + wr * 8192;
        const bf16* Bcur = SB + d * 16384 + (wc >> 1) * 8192;

        auto loadAF = [&](int IH) {
            #pragma unroll
            for (int i2 = 0; i2 < 4; i2++)
                #pragma unroll
                for (int ks = 0; ks < 2; ks++)
                    af[i2][ks] = *(const bf16x8*)&Acur[
                        (IH * 64 + i2 * 16 + l16) * 64 + (((ks * 4 + quad) ^ (l16 & 7)) * 8)];
        };
        auto loadBF = [&](int JH) {
            #pragma unroll
            for (int j2 = 0; j2 < 2; j2++)
                #pragma unroll
                for (int ks = 0; ks < 2; ks++)
                    bf[j2][ks] = *(const bf16x8*)&Bcur[
                        ((wc & 1) * 64 + JH * 32 + j2 * 16 + l16) * 64 +
                        (((ks * 4 + quad) ^ (l16 & 7)) * 8)];
        };
        auto mfmaQ = [&](int IB, int JB) {
            __builtin_amdgcn_s_setprio(1);
            #pragma unroll
            for (int ks = 0; ks < 2; ks++)
                #pragma unroll
                for (int i2 = 0; i2 < 4; i2++)
                    #pragma unroll
                    for (int j2 = 0; j2 < 2; j2++)
                        acc[IB + i2][JB + j2] =
                            MFMA16(af[i2][ks], bf[j2][ks], acc[IB + i2][JB + j2]);
            __builtin_amdgcn_s_setprio(0);
        };

        // ---- p0 ----
        loadAF(0); loadBF(0);
        if (w < 15) stageB(w + 1, 0);
        __builtin_amdgcn_sched_barrier(0);
        __builtin_amdgcn_s_barrier();
        __builtin_amdgcn_sched_barrier(0);
        mfmaQ(0, 0);
        __builtin_amdgcn_s_barrier();
        __builtin_amdgcn_sched_barrier(0);
        // ---- p1 ----
        loadBF(1);
        if (w < 15) stageB(w + 1, 1);
        __builtin_amdgcn_sched_barrier(0);
        __builtin_amdgcn_s_barrier();
        __builtin_amdgcn_sched_barrier(0);
        mfmaQ(0, 2);
        __builtin_amdgcn_s_barrier();
        __builtin_amdgcn_sched_barrier(0);
        // ---- p2 ----
        loadAF(1);
        __builtin_amdgcn_sched_barrier(0);
        __builtin_amdgcn_s_barrier();
        __builtin_amdgcn_sched_barrier(0);
        mfmaQ(4, 2);
        __builtin_amdgcn_s_barrier();
        __builtin_amdgcn_sched_barrier(0);
        // ---- p3 ----
        loadBF(0);
        if (w < 14) { stageA(w + 2, 0); stageA(w + 2, 1); }
        __builtin_amdgcn_sched_barrier(0);
        __builtin_amdgcn_s_barrier();
        __builtin_amdgcn_sched_barrier(0);
        mfmaQ(4, 0);
        if (w < 14)       asm volatile("s_waitcnt vmcnt(4)" ::: "memory");
        else if (w == 14) asm volatile("s_waitcnt vmcnt(0)" ::: "memory");
        __builtin_amdgcn_sched_barrier(0);
        __builtin_amdgcn_s_barrier();
        __builtin_amdgcn_sched_barrier(0);
    }

    // ---- epilogue (verified in rounds 1-2 at this exact geometry) ----
    if (mode == 3) {
        bf16* Y3 = (bf16*)smem;                      // [128][264]
        #pragma unroll
        for (int h = 0; h < 2; h++) {
            if ((wc >> 1) == h) {
                #pragma unroll
                for (int j = 0; j < 4; j++) {
                    const int nl = (wc & 1) * 64 + j * 16 + l16;
                    const float bv = bias[n0 + wc * 64 + j * 16 + l16];
                    #pragma unroll
                    for (int i = 0; i < 8; i++) {
                        bf16 tmp[4];
                        #pragma unroll
                        for (int r = 0; r < 4; r++) tmp[r] = (bf16)(acc[i][j][r] + bv);
                        *(ushort4*)&Y3[nl * 264 + wr * 128 + i * 16 + quad * 4] =
                            *(const ushort4*)tmp;
                    }
                }
            }
            __syncthreads();
            const int nl = tid >> 5, m8 = (tid & 31) * 8;
            #pragma unroll
            for (int kk = 0; kk < 8; kk++)
                *(uint4*)&out[(size_t)(n0 + h * 128 + nl + kk * 16) * kNTOK + m0 + m8] =
                    *(const uint4*)&Y3[(nl + kk * 16) * 264 + m8];
            __syncthreads();
        }
    } else {
        bf16* Y = (bf16*)smem;                       // [256][136]
        #pragma unroll
        for (int h = 0; h < 2; h++) {
            if ((wc >> 1) == h && (wc & 1)) {        // deposit x2 (d in [64,128))
                #pragma unroll
                for (int j = 0; j < 4; j++) {
                    const int dj = j * 16 + l16;
                    const float bv = bias[n0 + wc * 64 + j * 16 + l16];
                    #pragma unroll
                    for (int i = 0; i < 8; i++)
                        #pragma unroll
                        for (int r = 0; r < 4; r++)
                            Y[(wr * 128 + i * 16 + quad * 4 + r) * 136 + 64 + dj] =
                                (bf16)(acc[i][j][r] + bv);
                }
            }
            __syncthreads();
            if ((wc >> 1) == h && !(wc & 1)) {       // rotate (d in [0,64))
                #pragma unroll
                for (int j = 0; j < 4; j++) {
                    const int d2 = j * 16 + l16;
                    const float bv = bias[n0 + wc * 64 + j * 16 + l16];
                    const float invf = exp2f((float)d2 * -0.20762050593045951f);
                    #pragma unroll
                    for (int i = 0; i < 8; i++) {
                        #pragma unroll
                        for (int r = 0; r < 4; r++) {
                            const int mloc = wr * 128 + i * 16 + quad * 4 + r;
                            const int tok = m0 + mloc;
                            int pt, ph, pw;
                            if (mode == 2) { pt = tok >> 10; ph = (tok >> 5) & 31; pw = tok & 31; }
                            else { int tq = tok >> 8; pt = (31 * tq) / 7;
                                   ph = 2 * ((tok >> 4) & 15) + 1; pw = 2 * (tok & 15) + 1; }
                            const int p = (d2 < 16) ? pt : ((d2 < 40) ? ph : pw);
                            float sn, cs;
                            __sincosf((float)p * invf, &sn, &cs);
                            const float x1 = acc[i][j][r] + bv;
                            const float x2 = (float)Y[mloc * 136 + 64 + d2];
                            Y[mloc * 136 + d2]      = (bf16)(x1 * cs - x2 * sn);
                            Y[mloc * 136 + 64 + d2] = (bf16)(x2 * cs + x1 * sn);
                        }
                    }
                }
            }
            __syncthreads();
            const int rrow = tid >> 1, seg = (tid & 1) * 64;
            #pragma unroll
            for (int kk = 0; kk < 8; kk++)
                *(uint4*)&out[(size_t)(m0 + rrow) * kDM + n0 + h * 128 + seg + kk * 8] =
                    *(const uint4*)&Y[rrow * 136 + seg + kk * 8];
            __syncthreads();
        }
    }
}

// Merged K (blocks 0..511, mode 2) + Q (blocks 512..543, mode 1) dispatch.
__global__ __launch_bounds__(512, 2) void gemm256_kq(
    const bf16* __restrict__ Xk, const bf16* __restrict__ Xq,
    const bf16* __restrict__ Wkt, const bf16* __restrict__ Wqt,
    const float* __restrict__ bk, const float* __restrict__ bq,
    bf16* __restrict__ kh, bf16* __restrict__ qh)
{
    int b = blockIdx.x;
    if (b < 512) {
        const int xcd = b & 7, s = b >> 3;
        gemm256_body(Xk, Wkt, bk, kh, (xcd * 16 + (s >> 2)) * 256, (s & 3) * 256, 2);
    } else {
        b -= 512;
        const int xcd = b & 7, s = b >> 3;
        gemm256_body(Xq, Wqt, bq, qh, xcd * 256, (s & 3) * 256, 1);
    }
}

__global__ __launch_bounds__(512, 2) void gemm256_v(
    const bf16* __restrict__ Xv, const bf16* __restrict__ Wvt,
    const float* __restrict__ bv, bf16* __restrict__ vt)
{
    const int b = blockIdx.x;
    const int xcd = b & 7, s = b >> 3;
    gemm256_body(Xv, Wvt, bv, vt, (xcd * 16 + (s >> 2)) * 256, (s & 3) * 256, 3);
}

// ---------------------------------------------------------------------------
// Flash attention, 4-way key split. Grid (z=32, h=8, qb=4) = 1024 blocks =
// exactly 4/CU at 40KB LDS. l (row-sum of P) via MFMA with all-ones B-frag.
// Ps XOR-swizzled.  T5 setprio around both MFMA clusters.
// ---------------------------------------------------------------------------
__global__ __launch_bounds__(256) void attn_kernel(
    const bf16* __restrict__ qh, const bf16* __restrict__ kh,
    const bf16* __restrict__ vt, float* __restrict__ Opart, float* __restrict__ ml)
{
    __shared__ bf16 Ks[64 * 128];    // [key][d], 16B-granule swizzle by key&15
    __shared__ bf16 Vs[128 * 64];    // [d][key], 16B-granule swizzle by d&7
    __shared__ bf16 Ps[4][16][64];   // per-wave P, col ^ ((row&7)*8) swizzle

    const int tid  = threadIdx.x;
    const int z    = blockIdx.x, h = blockIdx.y, qb = blockIdx.z;
    const int t    = z >> 2, sp = z & 3;
    const int wave = tid >> 6;
    const int lane = tid & 63;
    const int quad = lane >> 4, l16 = lane & 15;

    const int qrow = qb * 64 + wave * 16 + l16;
    const size_t qbase = ((size_t)(t * 256 + qrow)) * kDM + h * 128;
    bf16x8 aq[4];
    #pragma unroll
    for (int kb = 0; kb < 4; kb++)
        aq[kb] = *(const bf16x8*)&qh[qbase + kb * 32 + quad * 8];

    bf16x8 ones;
    #pragma unroll
    for (int e = 0; e < 8; e++) ones[e] = (bf16)1.0f;

    f32x4 o[9];
    #pragma unroll
    for (int j = 0; j < 9; j++) o[j] = zero4();
    float m_run[4];
    #pragma unroll
    for (int r = 0; r < 4; r++) m_run[r] = -1e30f;
    const float scale = 0.08838834764831845f;   // 1/sqrt(128)

    const int r16 = lane >> 4, j16 = lane & 15;  // K staging coords
    const int r8  = lane >> 3, j8  = lane & 7;   // V staging coords

    for (int kt = 0; kt < 16; kt++) {
        const int kbase = t * 4096 + sp * 1024 + kt * 64;
        __syncthreads();
        #pragma unroll
        for (int i = 0; i < 4; i++) {   // K: 16 chunks (4 key rows each)
            const int c = wave * 4 + i;
            const int krow = c * 4 + r16;
            GLOAD_LDS16(&kh[(size_t)(kbase + krow) * kDM + h * 128 + ((j16 ^ (krow & 15)) * 8)],
                        &Ks[c * 512]);
        }
        #pragma unroll
        for (int i = 0; i < 4; i++) {   // V^T: 16 chunks (8 d rows x 64 keys)
            const int c = wave * 4 + i;
            GLOAD_LDS16(&vt[(size_t)(h * 128 + c * 8 + r8) * kNTOK + kbase + ((j8 ^ r8) * 8)],
                        &Vs[c * 512]);
        }
        __syncthreads();

        // S = Q K^T : 16 q x 64 keys per wave
        f32x4 s[4];
        #pragma unroll
        for (int c = 0; c < 4; c++) s[c] = zero4();
        __builtin_amdgcn_s_setprio(1);
        #pragma unroll
        for (int kb = 0; kb < 4; kb++) {
            #pragma unroll
            for (int c = 0; c < 4; c++) {
                bf16x8 b = *(const bf16x8*)&Ks[(c * 16 + l16) * 128 + (((kb * 4 + quad) ^ l16) * 8)];
                s[c] = MFMA16(aq[kb], b, s[c]);
            }
        }
        __builtin_amdgcn_s_setprio(0);

        // online softmax (max via shfl; sum via ones-frag MFMA)
        float alpha[4];
        #pragma unroll
        for (int r = 0; r < 4; r++) {
            float sv[4];
            #pragma unroll
            for (int c = 0; c < 4; c++) sv[c] = s[c][r] * scale;
            float mx = fmaxf(fmaxf(sv[0], sv[1]), fmaxf(sv[2], sv[3]));
            #pragma unroll
            for (int off = 1; off < 16; off <<= 1) mx = fmaxf(mx, __shfl_xor(mx, off));
            const float mn = fmaxf(m_run[r], mx);
            alpha[r] = __expf(m_run[r] - mn);
            m_run[r] = mn;
            const int q7 = quad * 4 + r;
            #pragma unroll
            for (int c = 0; c < 4; c++) {
                const int col = (c * 16 + l16) ^ ((q7 & 7) * 8);
                Ps[wave][q7][col] = (bf16)__expf(sv[c] - mn);
            }
        }
        #pragma unroll
        for (int j = 0; j < 9; j++)
            #pragma unroll
            for (int r = 0; r < 4; r++) o[j][r] *= alpha[r];
        __builtin_amdgcn_s_setprio(1);
        #pragma unroll
        for (int ks = 0; ks < 2; ks++) {
            bf16x8 pa = *(const bf16x8*)&Ps[wave][l16][((ks * 4 + quad) ^ (l16 & 7)) * 8];
            #pragma unroll
            for (int j = 0; j < 8; j++) {
                bf16x8 bv = *(const bf16x8*)&Vs[(j * 16 + l16) * 64 + (((ks * 4 + quad) ^ (l16 & 7)) * 8)];
                o[j] = MFMA16(pa, bv, o[j]);
            }
            o[8] = MFMA16(pa, ones, o[8]);
        }
        __builtin_amdgcn_s_setprio(0);
    }

    #pragma unroll
    for (int r = 0; r < 4; r++) {
        const int srow = qb * 64 + wave * 16 + quad * 4 + r;
        const size_t pr = ((size_t)(z * 8 + h)) * 256 + srow;
        #pragma unroll
        for (int j = 0; j < 8; j++)
            Opart[pr * 128 + j * 16 + l16] = o[j][r];
        if (l16 == 0) { ml[pr * 2] = m_run[r]; ml[pr * 2 + 1] = o[8][r]; }
    }
}

// ---------------------------------------------------------------------------
// Combine 4 splits: O = sum O_sp*exp(m_sp-m*) / sum l_sp*exp(m_sp-m*)
// ---------------------------------------------------------------------------
__global__ __launch_bounds__(256) void combine_kernel(
    const float* __restrict__ Opart, const float* __restrict__ ml,
    float* __restrict__ out)
{
    const int tid = threadIdx.x;
    const int rid = blockIdx.x * 2 + (tid >> 7);
    const int d   = tid & 127;
    const int t = rid >> 11, h = (rid >> 8) & 7, srow = rid & 255;

    float mv[4], lv[4];
    #pragma unroll
    for (int sp = 0; sp < 4; sp++) {
        const size_t pr = ((size_t)((t * 4 + sp) * 8 + h)) * 256 + srow;
        float2 p = *(const float2*)&ml[pr * 2];
        mv[sp] = p.x; lv[sp] = p.y;
    }
    const float ms = fmaxf(fmaxf(mv[0], mv[1]), fmaxf(mv[2], mv[3]));
    float lsum = 0.f, acc = 0.f;
    #pragma unroll
    for (int sp = 0; sp < 4; sp++) {
        const size_t pr = ((size_t)((t * 4 + sp) * 8 + h)) * 256 + srow;
        const float w = __expf(mv[sp] - ms);
        lsum += lv[sp] * w;
        acc  += Opart[pr * 128 + d] * w;
    }
    out[((size_t)(t * 256 + srow)) * kDM + h * 128 + d] = acc / lsum;
}

// ---------------------------------------------------------------------------
extern "C" void kernel_launch(void* const* d_in, const int* in_sizes, int n_in,
                              void* d_out, int out_size, void* d_ws, size_t ws_size,
                              hipStream_t stream)
{
    const float* q  = (const float*)d_in[0];
    const float* k  = (const float*)d_in[1];
    const float* v  = (const float*)d_in[2];
    const float* Wq = (const float*)d_in[3];
    const float* bq = (const float*)d_in[4];
    const float* Wk = (const float*)d_in[5];
    const float* bk = (const float*)d_in[6];
    const float* Wv = (const float*)d_in[7];
    const float* bv = (const float*)d_in[8];
    float* out = (float*)d_out;

    // ws: qh 4MB | kh 64MB | vt 64MB | Wt x3 6MB | Opart 33.5MB | ml 0.5MB |
    //     Xb 68MB (bf16: q 4MB + k 64MB; later reused for v 64MB)
    bf16* qh  = (bf16*)d_ws;
    bf16* kh  = qh + (size_t)2048 * 1024;
    bf16* vt  = kh + (size_t)32768 * 1024;
    bf16* Wqt = vt + (size_t)32768 * 1024;
    bf16* Wkt = Wqt + (size_t)1024 * 1024;
    bf16* Wvt = Wkt + (size_t)1024 * 1024;
    float* Opart = (float*)(Wvt + (size_t)1024 * 1024);
    float* ml    = Opart + (size_t)32 * 8 * 256 * 128;
    bf16* Xb     = (bf16*)(ml + (size_t)32 * 8 * 256 * 2);
    bf16* Xq     = Xb;
    bf16* Xk     = Xb + (size_t)2048 * 1024;

    transpose_all<<<dim3(16, 16, 3), 256, 0, stream>>>(Wq, Wk, Wv, Wqt, Wkt, Wvt);

    cvt_qk<<<2048, 256, 0, stream>>>(q, k, Xb);
    gemm256_kq<<<544, 512, 0, stream>>>(Xk, Xq, Wkt, Wqt, bk, bq, kh, qh);

    cvt_bf16<<<2048, 256, 0, stream>>>(v, Xb, 32768 * 1024 / 8);
    gemm256_v<<<512, 512, 0, stream>>>(Xb, Wvt, bv, vt);

    attn_kernel<<<dim3(32, 8, 4), 256, 0, stream>>>(qh, kh, vt, Opart, ml);
    combine_kernel<<<8192, 256, 0, stream>>>(Opart, ml, out);
}

// Round 6
// 611.853 us; speedup vs baseline: 1.0368x; 1.0368x over previous
//
#include <hip/hip_runtime.h>

typedef __bf16 bf16;
typedef __bf16 bf16x8 __attribute__((ext_vector_type(8)));
typedef float  f32x4  __attribute__((ext_vector_type(4)));

#define MFMA16(a, b, c) __builtin_amdgcn_mfma_f32_16x16x32_bf16((a), (b), (c), 0, 0, 0)

// async global->LDS, 16B per lane; LDS dest = wave-uniform base + lane*16
#define GLOAD_LDS16(gptr, lptr)                                              \
    __builtin_amdgcn_global_load_lds(                                        \
        (const __attribute__((address_space(1))) unsigned int*)(gptr),       \
        (__attribute__((address_space(3))) unsigned int*)(lptr), 16, 0, 0)

constexpr int kDM = 1024;
constexpr int kNTOK = 32768;   // V token count (vt row stride)

static __device__ inline f32x4 zero4() { f32x4 z = {0.f, 0.f, 0.f, 0.f}; return z; }

// ---------------------------------------------------------------------------
// Streaming fp32 -> bf16 convert for q and k in ONE launch (RNE rounding).
// dst layout: q bf16 [2048*1024] followed by k bf16 [32768*1024].
// ---------------------------------------------------------------------------
__global__ __launch_bounds__(256) void cvt_qk(
    const float* __restrict__ q, const float* __restrict__ k, bf16* __restrict__ dst)
{
    const int q8 = 262144, tot = q8 + 4194304;
    int idx = blockIdx.x * 256 + threadIdx.x;
    const int stride = gridDim.x * 256;
    for (; idx < tot; idx += stride) {
        const float* s = (idx < q8) ? q + (size_t)idx * 8
                                    : k + (size_t)(idx - q8) * 8;
        const float4 u0 = *(const float4*)s;
        const float4 u1 = *(const float4*)(s + 4);
        bf16x8 w;
        w[0] = (bf16)u0.x; w[1] = (bf16)u0.y; w[2] = (bf16)u0.z; w[3] = (bf16)u0.w;
        w[4] = (bf16)u1.x; w[5] = (bf16)u1.y; w[6] = (bf16)u1.z; w[7] = (bf16)u1.w;
        *(bf16x8*)&dst[(size_t)idx * 8] = w;
    }
}

__global__ __launch_bounds__(256) void cvt_bf16(
    const float* __restrict__ src, bf16* __restrict__ dst, int n8)
{
    int idx = blockIdx.x * 256 + threadIdx.x;
    const int stride = gridDim.x * 256;
    for (; idx < n8; idx += stride) {
        const float4 u0 = *(const float4*)(src + (size_t)idx * 8);
        const float4 u1 = *(const float4*)(src + (size_t)idx * 8 + 4);
        bf16x8 w;
        w[0] = (bf16)u0.x; w[1] = (bf16)u0.y; w[2] = (bf16)u0.z; w[3] = (bf16)u0.w;
        w[4] = (bf16)u1.x; w[5] = (bf16)u1.y; w[6] = (bf16)u1.z; w[7] = (bf16)u1.w;
        *(bf16x8*)&dst[(size_t)idx * 8] = w;
    }
}

// ---------------------------------------------------------------------------
// All three W fp32 [k][n] -> Wt bf16 [n][k] transposes in one launch.
// ---------------------------------------------------------------------------
__global__ __launch_bounds__(256) void transpose_all(
    const float* __restrict__ Wq, const float* __restrict__ Wk,
    const float* __restrict__ Wv, bf16* __restrict__ Wqt,
    bf16* __restrict__ Wkt, bf16* __restrict__ Wvt)
{
    __shared__ bf16 T[64][68];
    const float* W = (blockIdx.z == 0) ? Wq : (blockIdx.z == 1) ? Wk : Wv;
    bf16* Wt       = (blockIdx.z == 0) ? Wqt : (blockIdx.z == 1) ? Wkt : Wvt;
    const int tid = threadIdx.x;
    const int n0 = blockIdx.x * 64, k0 = blockIdx.y * 64;
    #pragma unroll
    for (int i = 0; i < 4; i++) {
        const int kk = (tid >> 4) + i * 16, nn4 = (tid & 15) * 4;
        float4 v = *(const float4*)&W[(size_t)(k0 + kk) * kDM + n0 + nn4];
        T[nn4 + 0][kk] = (bf16)v.x; T[nn4 + 1][kk] = (bf16)v.y;
        T[nn4 + 2][kk] = (bf16)v.z; T[nn4 + 3][kk] = (bf16)v.w;
    }
    __syncthreads();
    #pragma unroll
    for (int i = 0; i < 4; i++) {
        const int nn = (tid >> 4) + i * 16, kc = (tid & 15) * 4;
        *(ushort4*)&Wt[(size_t)(n0 + nn) * kDM + k0 + kc] = *(const ushort4*)&T[nn][kc];
    }
}

// ---------------------------------------------------------------------------
// GEMM + fused epilogue: out = Xb_bf16[M][1024] @ Wt_bf16[N][K]^T + bias
// 128x128 tile, BK=64, 4 waves 2x2.  Double-buffered staging (2x32KB LDS),
// both operands via global_load_lds w=16 (linear dest, XOR-pre-swizzled
// source).  Per K-step: issue next tile's 8 loads FIRST, compute current
// tile, then ONE vmcnt(0)+s_barrier.  (Round-4 verified: 108.5us, 633 TF.)
// MODE 1: slow RoPE (q).  MODE 2: fast RoPE (k).  MODE 3: V^T store.
// ---------------------------------------------------------------------------
template <int MODE>
__global__ __launch_bounds__(256) void gemm_fused(
    const bf16* __restrict__ Xb, const bf16* __restrict__ Wt,
    const float* __restrict__ bias, bf16* __restrict__ out, int mtiles_per_xcd)
{
    __shared__ char smem[65536];         // 2 x {A [128][64], B [128][64]} bf16
    bf16* Y = (bf16*)smem;               // epilogue buffer [128][136] (34.8KB)

    const int b    = blockIdx.x;
    const int xcd  = b & 7;
    const int s    = b >> 3;
    const int m0   = (xcd * mtiles_per_xcd + (s >> 3)) * 128;
    const int n0   = (s & 7) * 128;
    const int tid  = threadIdx.x;
    const int wave = tid >> 6;
    const int lane = tid & 63;
    const int quad = lane >> 4, l16 = lane & 15;
    const int mb   = (wave & 1) * 64, nb = (wave >> 1) * 64;
    const int r8   = lane >> 3, j8 = lane & 7;   // staging coords

    f32x4 acc[4][4];
    #pragma unroll
    for (int i = 0; i < 4; i++)
        #pragma unroll
        for (int j = 0; j < 4; j++) acc[i][j] = zero4();

    // stage one 64-K slab of A and B into buffer `buf` (8 gload_lds/thread)
    auto stage = [&](int k0, char* buf) {
        bf16* Ab = (bf16*)buf;
        bf16* Bb = (bf16*)(buf + 16384);
        #pragma unroll
        for (int i = 0; i < 4; i++) {
            const int c = wave * 4 + i;
            const int row = c * 8 + r8;
            const int off = (j8 ^ (row & 7)) * 8;
            GLOAD_LDS16(&Xb[(size_t)(m0 + row) * kDM + k0 + off], &Ab[c * 512]);
            GLOAD_LDS16(&Wt[(size_t)(n0 + row) * kDM + k0 + off], &Bb[c * 512]);
        }
    };

    // prologue: stage tile 0
    stage(0, smem);
    asm volatile("s_waitcnt vmcnt(0)" ::: "memory");
    __builtin_amdgcn_s_barrier();

    for (int t = 0; t < 16; ++t) {
        const char* cur = smem + (t & 1) * 32768;
        if (t < 15) stage((t + 1) * 64, smem + ((t + 1) & 1) * 32768);
        __builtin_amdgcn_sched_barrier(0);   // pin prefetch issue above compute

        const bf16* Ab = (const bf16*)cur;
        const bf16* Bb = (const bf16*)(cur + 16384);
        #pragma unroll
        for (int ks = 0; ks < 2; ks++) {
            const int G = ks * 4 + quad;
            bf16x8 a[4], bfr[4];
            #pragma unroll
            for (int i = 0; i < 4; i++)
                a[i] = *(const bf16x8*)&Ab[(mb + i * 16 + l16) * 64 + ((G ^ (l16 & 7)) * 8)];
            #pragma unroll
            for (int j = 0; j < 4; j++)
                bfr[j] = *(const bf16x8*)&Bb[(nb + j * 16 + l16) * 64 + ((G ^ (l16 & 7)) * 8)];
            #pragma unroll
            for (int i = 0; i < 4; i++)
                #pragma unroll
                for (int j = 0; j < 4; j++)
                    acc[i][j] = MFMA16(a[i], bfr[j], acc[i][j]);
        }

        if (t < 15) asm volatile("s_waitcnt vmcnt(0)" ::: "memory");  // next tile landed
        __builtin_amdgcn_sched_barrier(0);
        __builtin_amdgcn_s_barrier();        // everyone done reading cur
    }

    __syncthreads();   // staging region about to be reused as Y

    if (MODE == 3) {
        // transposed epilogue: Y[n][m], then vectorized store to out[n][token]
        #pragma unroll
        for (int j = 0; j < 4; j++) {
            const int n = nb + j * 16 + l16;
            const float bv = bias[n0 + n];
            #pragma unroll
            for (int i = 0; i < 4; i++) {
                const int m = mb + i * 16 + quad * 4;
                bf16 tmp[4];
                #pragma unroll
                for (int r = 0; r < 4; r++) tmp[r] = (bf16)(acc[i][j][r] + bv);
                *(ushort4*)&Y[n * 136 + m] = *(const ushort4*)tmp;
            }
        }
        __syncthreads();
        const int row = tid >> 1, seg = (tid & 1) * 64;
        #pragma unroll
        for (int kk = 0; kk < 8; kk++)
            *(uint4*)&out[(size_t)(n0 + row) * kNTOK + m0 + seg + kk * 8] =
                *(const uint4*)&Y[row * 136 + seg + kk * 8];
    } else {
        // RoPE epilogue. phase 1: waves 2,3 deposit x2 (d in [64,128)).
        if (wave >= 2) {
            #pragma unroll
            for (int j = 0; j < 4; j++) {
                const int dcol = 64 + j * 16 + l16;
                const float bv = bias[n0 + dcol];
                #pragma unroll
                for (int i = 0; i < 4; i++)
                    #pragma unroll
                    for (int r = 0; r < 4; r++)
                        Y[(mb + i * 16 + quad * 4 + r) * 136 + dcol] =
                            (bf16)(acc[i][j][r] + bv);
            }
        }
        __syncthreads();
        // phase 2: waves 0,1 rotate (they hold x1, d in [0,64))
        if (wave < 2) {
            #pragma unroll
            for (int j = 0; j < 4; j++) {
                const int d = j * 16 + l16;
                const float bv = bias[n0 + d];
                const float invf = exp2f((float)d * -0.20762050593045951f); // log2(1e4)/64
                #pragma unroll
                for (int i = 0; i < 4; i++) {
                    #pragma unroll
                    for (int r = 0; r < 4; r++) {
                        const int mloc = mb + i * 16 + quad * 4 + r;
                        const int tok = m0 + mloc;
                        int pt, ph, pw;
                        if (MODE == 2) { pt = tok >> 10; ph = (tok >> 5) & 31; pw = tok & 31; }
                        else { int tq = tok >> 8; pt = (31 * tq) / 7;
                               ph = 2 * ((tok >> 4) & 15) + 1; pw = 2 * (tok & 15) + 1; }
                        const int p = (d < 16) ? pt : ((d < 40) ? ph : pw);
                        float sn, cs;
                        __sincosf((float)p * invf, &sn, &cs);
                        const float x1 = acc[i][j][r] + bv;
                        const float x2 = (float)Y[mloc * 136 + 64 + d];
                        Y[mloc * 136 + d]      = (bf16)(x1 * cs - x2 * sn);
                        Y[mloc * 136 + 64 + d] = (bf16)(x2 * cs + x1 * sn);
                    }
                }
            }
        }
        __syncthreads();
        const int row = tid >> 1, seg = (tid & 1) * 64;
        #pragma unroll
        for (int kk = 0; kk < 8; kk++)
            *(uint4*)&out[(size_t)(m0 + row) * kDM + n0 + seg + kk * 8] =
                *(const uint4*)&Y[row * 136 + seg + kk * 8];
    }
}

// ---------------------------------------------------------------------------
// Flash attention, 4-way key split.  Flat 1024-block grid with XCD-aware
// sibling placement: the 4 qb-blocks sharing one (t,sp,h) K/V slice (512KB)
// are 8 apart in flat id -> consecutive on the SAME XCD -> the slice is
// L2-resident for the 3 re-readers (HBM traffic ~4x down).
// l (row-sum of P) via MFMA with all-ones B-frag; Ps XOR-swizzled; T5
// setprio around both MFMA clusters.
// ---------------------------------------------------------------------------
__global__ __launch_bounds__(256) void attn_kernel(
    const bf16* __restrict__ qh, const bf16* __restrict__ kh,
    const bf16* __restrict__ vt, float* __restrict__ Opart, float* __restrict__ ml)
{
    __shared__ bf16 Ks[64 * 128];    // [key][d], 16B-granule swizzle by key&15
    __shared__ bf16 Vs[128 * 64];    // [d][key], 16B-granule swizzle by d&7
    __shared__ bf16 Ps[4][16][64];   // per-wave P, col ^ ((row&7)*8) swizzle

    const int tid  = threadIdx.x;
    // sibling-aware decode: xcd = b&7 owns groups [xcd*32, xcd*32+32);
    // j = b>>3 walks (group, qb) with qb fastest.
    const int b    = blockIdx.x;
    const int j    = b >> 3;
    const int g    = (b & 7) * 32 + (j >> 2);   // (z,h) group in [0,256)
    const int qb   = j & 3;
    const int h    = g & 7;
    const int z    = g >> 3;
    const int t    = z >> 2, sp = z & 3;
    const int wave = tid >> 6;
    const int lane = tid & 63;
    const int quad = lane >> 4, l16 = lane & 15;

    const int qrow = qb * 64 + wave * 16 + l16;
    const size_t qbase = ((size_t)(t * 256 + qrow)) * kDM + h * 128;
    bf16x8 aq[4];
    #pragma unroll
    for (int kb = 0; kb < 4; kb++)
        aq[kb] = *(const bf16x8*)&qh[qbase + kb * 32 + quad * 8];

    bf16x8 ones;
    #pragma unroll
    for (int e = 0; e < 8; e++) ones[e] = (bf16)1.0f;

    f32x4 o[9];
    #pragma unroll
    for (int j2 = 0; j2 < 9; j2++) o[j2] = zero4();
    float m_run[4];
    #pragma unroll
    for (int r = 0; r < 4; r++) m_run[r] = -1e30f;
    const float scale = 0.08838834764831845f;   // 1/sqrt(128)

    const int r16 = lane >> 4, j16 = lane & 15;  // K staging coords
    const int r8  = lane >> 3, j8  = lane & 7;   // V staging coords

    for (int kt = 0; kt < 16; kt++) {
        const int kbase = t * 4096 + sp * 1024 + kt * 64;
        __syncthreads();
        #pragma unroll
        for (int i = 0; i < 4; i++) {   // K: 16 chunks (4 key rows each)
            const int c = wave * 4 + i;
            const int krow = c * 4 + r16;
            GLOAD_LDS16(&kh[(size_t)(kbase + krow) * kDM + h * 128 + ((j16 ^ (krow & 15)) * 8)],
                        &Ks[c * 512]);
        }
        #pragma unroll
        for (int i = 0; i < 4; i++) {   // V^T: 16 chunks (8 d rows x 64 keys)
            const int c = wave * 4 + i;
            GLOAD_LDS16(&vt[(size_t)(h * 128 + c * 8 + r8) * kNTOK + kbase + ((j8 ^ r8) * 8)],
                        &Vs[c * 512]);
        }
        __syncthreads();

        // S = Q K^T : 16 q x 64 keys per wave
        f32x4 s[4];
        #pragma unroll
        for (int c = 0; c < 4; c++) s[c] = zero4();
        __builtin_amdgcn_s_setprio(1);
        #pragma unroll
        for (int kb = 0; kb < 4; kb++) {
            #pragma unroll
            for (int c = 0; c < 4; c++) {
                bf16x8 bfr = *(const bf16x8*)&Ks[(c * 16 + l16) * 128 + (((kb * 4 + quad) ^ l16) * 8)];
                s[c] = MFMA16(aq[kb], bfr, s[c]);
            }
        }
        __builtin_amdgcn_s_setprio(0);

        // online softmax (max via shfl; sum via ones-frag MFMA)
        float alpha[4];
        #pragma unroll
        for (int r = 0; r < 4; r++) {
            float sv[4];
            #pragma unroll
            for (int c = 0; c < 4; c++) sv[c] = s[c][r] * scale;
            float mx = fmaxf(fmaxf(sv[0], sv[1]), fmaxf(sv[2], sv[3]));
            #pragma unroll
            for (int off = 1; off < 16; off <<= 1) mx = fmaxf(mx, __shfl_xor(mx, off));
            const float mn = fmaxf(m_run[r], mx);
            alpha[r] = __expf(m_run[r] - mn);
            m_run[r] = mn;
            const int q7 = quad * 4 + r;
            #pragma unroll
            for (int c = 0; c < 4; c++) {
                const int col = (c * 16 + l16) ^ ((q7 & 7) * 8);
                Ps[wave][q7][col] = (bf16)__expf(sv[c] - mn);
            }
        }
        #pragma unroll
        for (int j2 = 0; j2 < 9; j2++)
            #pragma unroll
            for (int r = 0; r < 4; r++) o[j2][r] *= alpha[r];
        __builtin_amdgcn_s_setprio(1);
        #pragma unroll
        for (int ks = 0; ks < 2; ks++) {
            bf16x8 pa = *(const bf16x8*)&Ps[wave][l16][((ks * 4 + quad) ^ (l16 & 7)) * 8];
            #pragma unroll
            for (int j2 = 0; j2 < 8; j2++) {
                bf16x8 bv = *(const bf16x8*)&Vs[(j2 * 16 + l16) * 64 + (((ks * 4 + quad) ^ (l16 & 7)) * 8)];
                o[j2] = MFMA16(pa, bv, o[j2]);
            }
            o[8] = MFMA16(pa, ones, o[8]);
        }
        __builtin_amdgcn_s_setprio(0);
    }

    #pragma unroll
    for (int r = 0; r < 4; r++) {
        const int srow = qb * 64 + wave * 16 + quad * 4 + r;
        const size_t pr = ((size_t)(z * 8 + h)) * 256 + srow;
        #pragma unroll
        for (int j2 = 0; j2 < 8; j2++)
            Opart[pr * 128 + j2 * 16 + l16] = o[j2][r];
        if (l16 == 0) { ml[pr * 2] = m_run[r]; ml[pr * 2 + 1] = o[8][r]; }
    }
}

// ---------------------------------------------------------------------------
// Combine 4 splits: O = sum O_sp*exp(m_sp-m*) / sum l_sp*exp(m_sp-m*)
// ---------------------------------------------------------------------------
__global__ __launch_bounds__(256) void combine_kernel(
    const float* __restrict__ Opart, const float* __restrict__ ml,
    float* __restrict__ out)
{
    const int tid = threadIdx.x;
    const int rid = blockIdx.x * 2 + (tid >> 7);
    const int d   = tid & 127;
    const int t = rid >> 11, h = (rid >> 8) & 7, srow = rid & 255;

    float mv[4], lv[4];
    #pragma unroll
    for (int sp = 0; sp < 4; sp++) {
        const size_t pr = ((size_t)((t * 4 + sp) * 8 + h)) * 256 + srow;
        float2 p = *(const float2*)&ml[pr * 2];
        mv[sp] = p.x; lv[sp] = p.y;
    }
    const float ms = fmaxf(fmaxf(mv[0], mv[1]), fmaxf(mv[2], mv[3]));
    float lsum = 0.f, acc = 0.f;
    #pragma unroll
    for (int sp = 0; sp < 4; sp++) {
        const size_t pr = ((size_t)((t * 4 + sp) * 8 + h)) * 256 + srow;
        const float w = __expf(mv[sp] - ms);
        lsum += lv[sp] * w;
        acc  += Opart[pr * 128 + d] * w;
    }
    out[((size_t)(t * 256 + srow)) * kDM + h * 128 + d] = acc / lsum;
}

// ---------------------------------------------------------------------------
extern "C" void kernel_launch(void* const* d_in, const int* in_sizes, int n_in,
                              void* d_out, int out_size, void* d_ws, size_t ws_size,
                              hipStream_t stream)
{
    const float* q  = (const float*)d_in[0];
    const float* k  = (const float*)d_in[1];
    const float* v  = (const float*)d_in[2];
    const float* Wq = (const float*)d_in[3];
    const float* bq = (const float*)d_in[4];
    const float* Wk = (const float*)d_in[5];
    const float* bk = (const float*)d_in[6];
    const float* Wv = (const float*)d_in[7];
    const float* bv = (const float*)d_in[8];
    float* out = (float*)d_out;

    // ws: qh 4MB | kh 64MB | vt 64MB | Wt x3 6MB | Opart 33.5MB | ml 0.5MB |
    //     Xb 68MB (bf16: q 4MB + k 64MB; later reused for v 64MB)
    bf16* qh  = (bf16*)d_ws;
    bf16* kh  = qh + (size_t)2048 * 1024;
    bf16* vt  = kh + (size_t)32768 * 1024;
    bf16* Wqt = vt + (size_t)32768 * 1024;
    bf16* Wkt = Wqt + (size_t)1024 * 1024;
    bf16* Wvt = Wkt + (size_t)1024 * 1024;
    float* Opart = (float*)(Wvt + (size_t)1024 * 1024);
    float* ml    = Opart + (size_t)32 * 8 * 256 * 128;
    bf16* Xb     = (bf16*)(ml + (size_t)32 * 8 * 256 * 2);
    bf16* Xq     = Xb;
    bf16* Xk     = Xb + (size_t)2048 * 1024;

    transpose_all<<<dim3(16, 16, 3), 256, 0, stream>>>(Wq, Wk, Wv, Wqt, Wkt, Wvt);

    cvt_qk<<<2048, 256, 0, stream>>>(q, k, Xb);
    gemm_fused<1><<<128,  256, 0, stream>>>(Xq, Wqt, bq, qh, 2);    // q proj + slow rope
    gemm_fused<2><<<2048, 256, 0, stream>>>(Xk, Wkt, bk, kh, 32);   // k proj + fast rope

    cvt_bf16<<<2048, 256, 0, stream>>>(v, Xb, 32768 * 1024 / 8);
    gemm_fused<3><<<2048, 256, 0, stream>>>(Xb, Wvt, bv, vt, 32);   // v proj, transposed

    attn_kernel<<<1024, 256, 0, stream>>>(qh, kh, vt, Opart, ml);
    combine_kernel<<<8192, 256, 0, stream>>>(Opart, ml, out);
}